// Round 3
// baseline (236.504 us; speedup 1.0000x reference)
//
#include <hip/hip_runtime.h>
#include <math.h>

// DeepHit loss, fully fused single persistent kernel.
// loss = -mean(log(prob+eps)) + 0.5 * mean_pair relu(risk_j - risk_i + 0.1)
// B=8192 rows, T=256 bins.
//
// Stage A: wave-per-row risk sum + survival product (float4 loads, shuffle
//          reductions). Writes pack[row]={risk,t,t_eff,0} + per-block ll partial.
// Stage B: ranking pairs over 2048 (256i x 128j) half-tile tasks, 4 per block,
//          branchless diagonal handling. Per-block {sum,cnt} partial.
// Stage C: block 0 reduces 512 partials -> out[0].
// Grid barriers: device-scope atomic counter + __threadfence (counters zeroed
// by a captured hipMemsetAsync every call -> graph-replay deterministic).

#define B_ROWS 8192
#define T_COLS 256
#define NB     512            // persistent blocks: 2 per CU, always co-resident
#define RPB    16             // rows per block in stage A
#define NTJ    64             // 128-row j half-tiles
#define NTASK  2048           // 32 i-tiles * 64 j-half-tiles

__device__ __forceinline__ void grid_barrier(unsigned int* c, unsigned int target) {
    __threadfence();                      // release: drain + make writes visible
    __syncthreads();
    if (threadIdx.x == 0) {
        __hip_atomic_fetch_add(c, 1u, __ATOMIC_ACQ_REL, __HIP_MEMORY_SCOPE_AGENT);
        while (__hip_atomic_load(c, __ATOMIC_ACQUIRE, __HIP_MEMORY_SCOPE_AGENT) < target) {
            __builtin_amdgcn_s_sleep(2);
        }
    }
    __syncthreads();
    __threadfence();                      // acquire: invalidate stale cache lines
}

__global__ __launch_bounds__(256, 2) void deephit_fused(
    const float* __restrict__ risk_probs,   // [B, T]
    const int*   __restrict__ times,        // [B]
    const int*   __restrict__ events,       // [B]
    float4*       __restrict__ pack,        // [B] {risk, t, t_eff, 0}
    float*        __restrict__ llpart,      // [NB]
    float*        __restrict__ rankpart,    // [NB]
    unsigned int* __restrict__ cntpart,     // [NB]
    unsigned int* __restrict__ ctr,         // [2] barrier counters (pre-zeroed)
    float*        __restrict__ out)         // [1]
{
    const int tid  = threadIdx.x;
    const int wid  = tid >> 6;
    const int lane = tid & 63;
    const int b    = blockIdx.x;

    // ---------------- Stage A: rows ----------------
    float llacc = 0.0f;   // only lane 0 accumulates

    int    rows[4];
    float4 h4[4];
    #pragma unroll
    for (int k = 0; k < 4; ++k) {         // issue all 4 row-loads up front
        rows[k] = b * RPB + k * 4 + wid;
        h4[k]   = reinterpret_cast<const float4*>(risk_probs)[rows[k] * 64 + lane];
    }

    #pragma unroll
    for (int k = 0; k < 4; ++k) {
        const int   row = rows[k];
        int tb = times[row];
        tb = max(0, min(tb, T_COLS - 1));
        const float4 h = h4[k];

        float rs = (h.x + h.y) + (h.z + h.w);          // sum_t h
        const int base = lane << 2;
        float p = 1.0f;                                // prod_{i<tb}(1-h_i)
        p *= (base + 0 < tb) ? (1.0f - h.x) : 1.0f;
        p *= (base + 1 < tb) ? (1.0f - h.y) : 1.0f;
        p *= (base + 2 < tb) ? (1.0f - h.z) : 1.0f;
        p *= (base + 3 < tb) ? (1.0f - h.w) : 1.0f;

        #pragma unroll
        for (int off = 32; off > 0; off >>= 1) {
            rs += __shfl_down(rs, off, 64);
            p  *= __shfl_down(p,  off, 64);
        }

        if (lane == 0) {
            const float ht = risk_probs[row * T_COLS + tb];   // L1-hot re-read
            const int   ev = events[row];
            // event: S(t-1)*h(t); censored: S(t-1)*(1-h(t))
            const float prob  = p * (ev == 1 ? ht : (1.0f - ht));
            const float teff  = (ev == 1) ? (float)tb : 1.0e9f;
            pack[row] = make_float4(rs, (float)tb, teff, 0.0f);
            llacc += logf(prob + 1e-8f);
        }
    }

    __shared__ float sll[4];
    if (lane == 0) sll[wid] = llacc;
    __syncthreads();
    if (tid == 0) llpart[b] = (sll[0] + sll[1]) + (sll[2] + sll[3]);

    grid_barrier(&ctr[0], NB);

    // ---------------- Stage B: ranking pairs ----------------
    // Task t = ti*64 + tjh: i in [ti*256, ti*256+256), j in [tjh*128, +128).
    // Active iff tjh >= 2*ti. Strict j>i via k > d, d = tid - (tjh-2ti)*128.
    __shared__ float2 sj[128];

    float        sum = 0.0f;
    unsigned int cnt = 0u;

    for (int q = 0; q < 4; ++q) {
        const int t   = b + q * NB;
        const int ti  = t >> 6;
        const int tjh = t & 63;
        const bool active = (tjh >= 2 * ti);

        __syncthreads();                  // protect sj reuse across tasks
        if (active && tid < 128) {
            const float4 pj = pack[tjh * 128 + tid];
            sj[tid] = make_float2(pj.x, pj.y);
        }
        __syncthreads();

        if (active) {
            const int    i     = ti * 256 + tid;
            const float4 pi    = pack[i];
            const float  ci    = pi.x - 0.1f;     // risk_i - margin
            const float  tieff = pi.z;
            const int    d     = tid - (tjh - 2 * ti) * 128;  // k>d <=> j>i

            #pragma unroll 4
            for (int k = 0; k < 128; ++k) {
                const float2 v  = sj[k];          // LDS broadcast
                const bool   ok = (k > d) & (v.y > tieff);
                sum += ok ? fmaxf(v.x - ci, 0.0f) : 0.0f;
                cnt += ok ? 1u : 0u;
            }
        }
    }

    #pragma unroll
    for (int off = 32; off > 0; off >>= 1) {
        sum += __shfl_down(sum, off, 64);
        cnt += (unsigned int)__shfl_down((int)cnt, off, 64);
    }
    __shared__ float        wsum[4];
    __shared__ unsigned int wcnt[4];
    if (lane == 0) { wsum[wid] = sum; wcnt[wid] = cnt; }
    __syncthreads();
    if (tid == 0) {
        rankpart[b] = (wsum[0] + wsum[1]) + (wsum[2] + wsum[3]);
        cntpart[b]  = wcnt[0] + wcnt[1] + wcnt[2] + wcnt[3];
    }

    grid_barrier(&ctr[1], NB);

    // ---------------- Stage C: final reduce (block 0) ----------------
    if (b == 0) {
        float        a  = llpart[tid]   + llpart[tid + 256];
        float        rb = rankpart[tid] + rankpart[tid + 256];
        unsigned int rc = cntpart[tid]  + cntpart[tid + 256];

        #pragma unroll
        for (int off = 32; off > 0; off >>= 1) {
            a  += __shfl_down(a,  off, 64);
            rb += __shfl_down(rb, off, 64);
            rc += (unsigned int)__shfl_down((int)rc, off, 64);
        }
        __shared__ float        fa[4], fb[4];
        __shared__ unsigned int fc[4];
        if (lane == 0) { fa[wid] = a; fb[wid] = rb; fc[wid] = rc; }
        __syncthreads();
        if (tid == 0) {
            const float        lls  = (fa[0] + fa[1]) + (fa[2] + fa[3]);
            const float        rsum = (fb[0] + fb[1]) + (fb[2] + fb[3]);
            const unsigned int n    = fc[0] + fc[1] + fc[2] + fc[3];
            const float ll   = -lls / (float)B_ROWS;
            const float rank = (n > 0u) ? (rsum / (float)n) : 0.0f;
            out[0] = ll + 0.5f * rank;
        }
    }
}

extern "C" void kernel_launch(void* const* d_in, const int* in_sizes, int n_in,
                              void* d_out, int out_size, void* d_ws, size_t ws_size,
                              hipStream_t stream) {
    const float* risk_probs = (const float*)d_in[0];
    const int*   times      = (const int*)d_in[1];
    const int*   events     = (const int*)d_in[2];
    float*       out        = (float*)d_out;

    // Workspace layout
    float4*       pack     = (float4*)d_ws;                                  // 128 KiB
    char*         base     = (char*)d_ws + B_ROWS * sizeof(float4);
    unsigned int* ctr      = (unsigned int*)base;                            // 16 B
    float*        llpart   = (float*)(base + 16);                            // [NB]
    float*        rankpart = llpart + NB;                                    // [NB]
    unsigned int* cntpart  = (unsigned int*)(rankpart + NB);                 // [NB]

    hipMemsetAsync(ctr, 0, 16, stream);   // reset barrier counters every call
    deephit_fused<<<NB, 256, 0, stream>>>(risk_probs, times, events,
                                          pack, llpart, rankpart, cntpart,
                                          ctr, out);
}

// Round 4
// 59.883 us; speedup vs baseline: 3.9495x; 3.9495x over previous
//
#include <hip/hip_runtime.h>
#include <math.h>

// DeepHit loss, 2-kernel pipeline (no grid barrier, no polling).
// loss = -mean(log(prob+eps)) + 0.5 * mean_pair relu(risk_j - risk_i + 0.1)
// B=8192 rows, T=256 bins.
//
// K1 rows_kernel: wave per row, float4 loads, shuffle reductions.
//                 pack[b]={risk_sum, t, t_eff, 0}, llpart[block]=sum log(prob+eps).
// K2 rank_kernel: 1056 perfectly-balanced tasks (256i x 128j half-tiles over the
//                 upper triangle), LDS float4 broadcast inner loop, per-block
//                 partial + fire-and-forget ticket atomic; last block does the
//                 deterministic f64 final reduce -> out[0].

#define B_ROWS   8192
#define T_COLS   256
#define K1_BLKS  2048          // 4 rows per block
#define NTASK    1056          // sum_{ti<32} (64 - 2*ti)

__global__ __launch_bounds__(256) void rows_kernel(
    const float* __restrict__ risk_probs,   // [B, T]
    const int*   __restrict__ times,        // [B]
    const int*   __restrict__ events,       // [B]
    float4* __restrict__ pack,              // [B] {risk, t, t_eff, 0}
    float*  __restrict__ llpart)            // [K1_BLKS]
{
    const int wid  = threadIdx.x >> 6;
    const int lane = threadIdx.x & 63;
    const int row  = (blockIdx.x << 2) + wid;

    const float4 h = reinterpret_cast<const float4*>(risk_probs)[row * 64 + lane];

    int tb = times[row];
    tb = max(0, min(tb, T_COLS - 1));

    float rs = (h.x + h.y) + (h.z + h.w);              // sum_t h
    const int base = lane << 2;
    float p = 1.0f;                                    // prod_{i<tb}(1-h_i)
    p *= (base + 0 < tb) ? (1.0f - h.x) : 1.0f;
    p *= (base + 1 < tb) ? (1.0f - h.y) : 1.0f;
    p *= (base + 2 < tb) ? (1.0f - h.z) : 1.0f;
    p *= (base + 3 < tb) ? (1.0f - h.w) : 1.0f;

    #pragma unroll
    for (int off = 32; off > 0; off >>= 1) {
        rs += __shfl_down(rs, off, 64);
        p  *= __shfl_down(p,  off, 64);
    }

    __shared__ float sll[4];
    if (lane == 0) {
        const float ht = risk_probs[row * T_COLS + tb];   // L1-hot
        const int   ev = events[row];
        // event: S(t-1)*h(t); censored: S(t-1)*(1-h(t))
        const float prob = p * (ev == 1 ? ht : (1.0f - ht));
        const float teff = (ev == 1) ? (float)tb : 1.0e9f;
        pack[row] = make_float4(rs, (float)tb, teff, 0.0f);
        sll[wid]  = logf(prob + 1e-8f);
    }
    __syncthreads();
    if (threadIdx.x == 0)
        llpart[blockIdx.x] = (sll[0] + sll[1]) + (sll[2] + sll[3]);
}

// Task t -> (ti, jh): ti(65-ti) <= t < (ti+1)(64-ti); jh = 2*ti + (t - ti*(65-ti)).
// Block covers i in [ti*256, +256), j in [jh*128, +128)  (all tasks active).
__global__ __launch_bounds__(256) void rank_kernel(
    const float4* __restrict__ pack,         // [B]
    const float*  __restrict__ llpart,       // [K1_BLKS]
    float*        __restrict__ rankpart,     // [NTASK]
    unsigned int* __restrict__ cntpart,      // [NTASK]
    unsigned int* __restrict__ ticket,       // [1], pre-zeroed
    float*        __restrict__ out)          // [1]
{
    const int tid = threadIdx.x;
    const int bt  = blockIdx.x;

    // invert task index (scalar, wave-uniform)
    int ti = (int)((65.0 - sqrt(4225.0 - 4.0 * (double)bt)) * 0.5);
    ti = max(0, min(ti, 31));
    while (ti > 0  && ti * (65 - ti) > bt) --ti;
    while (ti < 31 && (ti + 1) * (64 - ti) <= bt) ++ti;
    const int jh = 2 * ti + (bt - ti * (65 - ti));

    __shared__ float2 sj[128];
    if (tid < 128) {
        const float4 pj = pack[jh * 128 + tid];
        sj[tid] = make_float2(pj.x, pj.y);
    }
    __syncthreads();

    const int    i     = ti * 256 + tid;
    const float4 pi    = pack[i];
    const float  ci    = pi.x - 0.1f;                 // risk_i - margin
    const float  tieff = pi.z;                        // 1e9 for non-events
    const int    d     = tid - (jh - 2 * ti) * 128;   // pass iff k2 > d

    float        sum = 0.0f;
    unsigned int cnt = 0u;
    const float4* sj4 = reinterpret_cast<const float4*>(sj);
    #pragma unroll 4
    for (int k = 0; k < 64; ++k) {
        const float4 v = sj4[k];                      // {r0,t0,r1,t1} broadcast
        const int k2 = k << 1;
        const bool ok0 = (k2     > d) & (v.y > tieff);
        const bool ok1 = (k2 + 1 > d) & (v.w > tieff);
        sum += ok0 ? fmaxf(v.x - ci, 0.0f) : 0.0f;
        sum += ok1 ? fmaxf(v.z - ci, 0.0f) : 0.0f;
        cnt += ok0 ? 1u : 0u;
        cnt += ok1 ? 1u : 0u;
    }

    #pragma unroll
    for (int off = 32; off > 0; off >>= 1) {
        sum += __shfl_down(sum, off, 64);
        cnt += (unsigned int)__shfl_down((int)cnt, off, 64);
    }
    __shared__ float        wsum[4];
    __shared__ unsigned int wcnt[4];
    if ((tid & 63) == 0) { wsum[tid >> 6] = sum; wcnt[tid >> 6] = cnt; }
    __syncthreads();

    __shared__ bool s_last;
    if (tid == 0) {
        rankpart[bt] = (wsum[0] + wsum[1]) + (wsum[2] + wsum[3]);
        cntpart[bt]  = wcnt[0] + wcnt[1] + wcnt[2] + wcnt[3];
        __threadfence();   // make partial visible before the ticket
        const unsigned int old =
            __hip_atomic_fetch_add(ticket, 1u, __ATOMIC_ACQ_REL, __HIP_MEMORY_SCOPE_AGENT);
        s_last = (old == NTASK - 1);
    }
    __syncthreads();
    if (!s_last) return;

    // ---- last block: deterministic final reduce ----
    __threadfence();
    double llsum = 0.0;
    for (int k = tid; k < K1_BLKS; k += 256) llsum += (double)llpart[k];

    double             rsum = 0.0;
    unsigned long long n    = 0ull;
    for (int k = tid; k < NTASK; k += 256) {
        rsum += (double)rankpart[k];
        n    += (unsigned long long)cntpart[k];
    }

    #pragma unroll
    for (int off = 32; off > 0; off >>= 1) {
        llsum += __shfl_down(llsum, off, 64);
        rsum  += __shfl_down(rsum,  off, 64);
        n     += (unsigned long long)__shfl_down((long long)n, off, 64);
    }
    __shared__ double             da[4], db[4];
    __shared__ unsigned long long dn[4];
    if ((tid & 63) == 0) { da[tid >> 6] = llsum; db[tid >> 6] = rsum; dn[tid >> 6] = n; }
    __syncthreads();
    if (tid == 0) {
        const double             L  = (da[0] + da[1]) + (da[2] + da[3]);
        const double             R  = (db[0] + db[1]) + (db[2] + db[3]);
        const unsigned long long NN = dn[0] + dn[1] + dn[2] + dn[3];
        const double rank = (NN > 0ull) ? (R / (double)NN) : 0.0;
        out[0] = (float)(-L / (double)B_ROWS + 0.5 * rank);
    }
}

extern "C" void kernel_launch(void* const* d_in, const int* in_sizes, int n_in,
                              void* d_out, int out_size, void* d_ws, size_t ws_size,
                              hipStream_t stream) {
    const float* risk_probs = (const float*)d_in[0];
    const int*   times      = (const int*)d_in[1];
    const int*   events     = (const int*)d_in[2];
    float*       out        = (float*)d_out;

    // Workspace layout
    float4*       pack     = (float4*)d_ws;                              // 128 KiB
    float*        llpart   = (float*)(pack + B_ROWS);                    // [K1_BLKS]
    float*        rankpart = llpart + K1_BLKS;                           // [NTASK]
    unsigned int* cntpart  = (unsigned int*)(rankpart + NTASK);          // [NTASK]
    unsigned int* ticket   = cntpart + NTASK;                            // [1]

    hipMemsetAsync(ticket, 0, sizeof(unsigned int), stream);
    rows_kernel<<<K1_BLKS, 256, 0, stream>>>(risk_probs, times, events, pack, llpart);
    rank_kernel<<<NTASK, 256, 0, stream>>>(pack, llpart, rankpart, cntpart, ticket, out);
}

// Round 5
// 25.777 us; speedup vs baseline: 9.1750x; 2.3231x over previous
//
#include <hip/hip_runtime.h>
#include <math.h>

// DeepHit loss, 3-kernel pipeline — NO device-scope fences/atomics anywhere
// (R4 showed per-block __threadfence + same-line agent atomics cost ~45 µs).
// loss = -mean(log(prob+eps)) + 0.5 * mean_pair relu(risk_j - risk_i + 0.1)
// B=8192 rows, T=256 bins.
//
// K1 rows_kernel : wave per row, float4 loads, shuffle reductions.
// K2 rank_kernel : 1056 balanced tasks (256i x 128j half-tiles, upper triangle),
//                  LDS float4 broadcast inner loop, plain partial stores.
// K3 final_kernel: one block, deterministic reduce of all partials -> out[0].

#define B_ROWS   8192
#define T_COLS   256
#define K1_BLKS  2048          // 4 rows per block
#define NTASK    1056          // sum_{ti<32} (64 - 2*ti)

__global__ __launch_bounds__(256) void rows_kernel(
    const float* __restrict__ risk_probs,   // [B, T]
    const int*   __restrict__ times,        // [B]
    const int*   __restrict__ events,       // [B]
    float4* __restrict__ pack,              // [B] {risk, t, t_eff, 0}
    float*  __restrict__ llpart)            // [K1_BLKS]
{
    const int wid  = threadIdx.x >> 6;
    const int lane = threadIdx.x & 63;
    const int row  = (blockIdx.x << 2) + wid;

    const float4 h = reinterpret_cast<const float4*>(risk_probs)[row * 64 + lane];

    int tb = times[row];
    tb = max(0, min(tb, T_COLS - 1));

    float rs = (h.x + h.y) + (h.z + h.w);              // sum_t h
    const int base = lane << 2;
    float p = 1.0f;                                    // prod_{i<tb}(1-h_i)
    p *= (base + 0 < tb) ? (1.0f - h.x) : 1.0f;
    p *= (base + 1 < tb) ? (1.0f - h.y) : 1.0f;
    p *= (base + 2 < tb) ? (1.0f - h.z) : 1.0f;
    p *= (base + 3 < tb) ? (1.0f - h.w) : 1.0f;

    #pragma unroll
    for (int off = 32; off > 0; off >>= 1) {
        rs += __shfl_down(rs, off, 64);
        p  *= __shfl_down(p,  off, 64);
    }

    __shared__ float sll[4];
    if (lane == 0) {
        const float ht = risk_probs[row * T_COLS + tb];   // L1-hot re-read
        const int   ev = events[row];
        // event: S(t-1)*h(t); censored: S(t-1)*(1-h(t))
        const float prob = p * (ev == 1 ? ht : (1.0f - ht));
        const float teff = (ev == 1) ? (float)tb : 1.0e9f;
        pack[row] = make_float4(rs, (float)tb, teff, 0.0f);
        sll[wid]  = logf(prob + 1e-8f);
    }
    __syncthreads();
    if (threadIdx.x == 0)
        llpart[blockIdx.x] = (sll[0] + sll[1]) + (sll[2] + sll[3]);
}

// Task bt -> (ti, jh): ti(65-ti) <= bt < (ti+1)(64-ti); jh = 2ti + (bt - ti(65-ti)).
// Block covers i in [ti*256, +256), j in [jh*128, +128); strict j>i via k > d.
__global__ __launch_bounds__(256) void rank_kernel(
    const float4* __restrict__ pack,         // [B]
    float*        __restrict__ rankpart,     // [NTASK]
    unsigned int* __restrict__ cntpart)      // [NTASK]
{
    const int tid = threadIdx.x;
    const int bt  = blockIdx.x;

    // invert task index (wave-uniform scalar)
    int ti = (int)((65.0f - sqrtf(4225.0f - 4.0f * (float)bt)) * 0.5f);
    ti = max(0, min(ti, 31));
    while (ti > 0  && ti * (65 - ti) > bt) --ti;
    while (ti < 31 && (ti + 1) * (64 - ti) <= bt) ++ti;
    const int jh = 2 * ti + (bt - ti * (65 - ti));

    __shared__ float2 sj[128];
    if (tid < 128) {
        const float4 pj = pack[jh * 128 + tid];
        sj[tid] = make_float2(pj.x, pj.y);
    }
    __syncthreads();

    const int    i     = ti * 256 + tid;
    const float4 pi    = pack[i];
    const float  ci    = pi.x - 0.1f;                 // risk_i - margin
    const float  tieff = pi.z;                        // 1e9 for non-events
    const int    d     = tid - (jh - 2 * ti) * 128;   // pass iff k > d

    float        sum = 0.0f;
    unsigned int cnt = 0u;
    const float4* sj4 = reinterpret_cast<const float4*>(sj);
    #pragma unroll 4
    for (int k = 0; k < 64; ++k) {
        const float4 v = sj4[k];                      // {r0,t0,r1,t1} broadcast
        const int k2 = k << 1;
        const bool ok0 = (k2     > d) & (v.y > tieff);
        const bool ok1 = (k2 + 1 > d) & (v.w > tieff);
        sum += ok0 ? fmaxf(v.x - ci, 0.0f) : 0.0f;
        sum += ok1 ? fmaxf(v.z - ci, 0.0f) : 0.0f;
        cnt += ok0 ? 1u : 0u;
        cnt += ok1 ? 1u : 0u;
    }

    #pragma unroll
    for (int off = 32; off > 0; off >>= 1) {
        sum += __shfl_down(sum, off, 64);
        cnt += (unsigned int)__shfl_down((int)cnt, off, 64);
    }
    __shared__ float        wsum[4];
    __shared__ unsigned int wcnt[4];
    if ((tid & 63) == 0) { wsum[tid >> 6] = sum; wcnt[tid >> 6] = cnt; }
    __syncthreads();
    if (tid == 0) {
        rankpart[bt] = (wsum[0] + wsum[1]) + (wsum[2] + wsum[3]);
        cntpart[bt]  = wcnt[0] + wcnt[1] + wcnt[2] + wcnt[3];
    }
}

__global__ __launch_bounds__(256) void final_kernel(
    const float*        __restrict__ llpart,    // [K1_BLKS]
    const float*        __restrict__ rankpart,  // [NTASK]
    const unsigned int* __restrict__ cntpart,   // [NTASK]
    float* __restrict__ out)
{
    const int tid = threadIdx.x;

    double llsum = 0.0;
    for (int k = tid; k < K1_BLKS; k += 256) llsum += (double)llpart[k];

    double             rsum = 0.0;
    unsigned long long n    = 0ull;
    for (int k = tid; k < NTASK; k += 256) {
        rsum += (double)rankpart[k];
        n    += (unsigned long long)cntpart[k];
    }

    #pragma unroll
    for (int off = 32; off > 0; off >>= 1) {
        llsum += __shfl_down(llsum, off, 64);
        rsum  += __shfl_down(rsum,  off, 64);
        n     += (unsigned long long)__shfl_down((long long)n, off, 64);
    }
    __shared__ double             da[4], db[4];
    __shared__ unsigned long long dn[4];
    if ((tid & 63) == 0) { da[tid >> 6] = llsum; db[tid >> 6] = rsum; dn[tid >> 6] = n; }
    __syncthreads();
    if (tid == 0) {
        const double             L  = (da[0] + da[1]) + (da[2] + da[3]);
        const double             R  = (db[0] + db[1]) + (db[2] + db[3]);
        const unsigned long long NN = dn[0] + dn[1] + dn[2] + dn[3];
        const double rank = (NN > 0ull) ? (R / (double)NN) : 0.0;
        out[0] = (float)(-L / (double)B_ROWS + 0.5 * rank);
    }
}

extern "C" void kernel_launch(void* const* d_in, const int* in_sizes, int n_in,
                              void* d_out, int out_size, void* d_ws, size_t ws_size,
                              hipStream_t stream) {
    const float* risk_probs = (const float*)d_in[0];
    const int*   times      = (const int*)d_in[1];
    const int*   events     = (const int*)d_in[2];
    float*       out        = (float*)d_out;

    // Workspace layout
    float4*       pack     = (float4*)d_ws;                              // 128 KiB
    float*        llpart   = (float*)(pack + B_ROWS);                    // [K1_BLKS]
    float*        rankpart = llpart + K1_BLKS;                           // [NTASK]
    unsigned int* cntpart  = (unsigned int*)(rankpart + NTASK);          // [NTASK]

    rows_kernel <<<K1_BLKS, 256, 0, stream>>>(risk_probs, times, events, pack, llpart);
    rank_kernel <<<NTASK,   256, 0, stream>>>(pack, rankpart, cntpart);
    final_kernel<<<1,       256, 0, stream>>>(llpart, rankpart, cntpart, out);
}